// Round 1
// baseline (661.178 us; speedup 1.0000x reference)
//
#include <hip/hip_runtime.h>

#define B_DIM 128
#define T_DIM 512
#define C_DIM 384
#define NH_DIM 6
#define HD_DIM 64
#define QKV_LD 1152  // 3*C

typedef __bf16 bf16x8 __attribute__((ext_vector_type(8)));
typedef __bf16 bf16x4 __attribute__((ext_vector_type(4)));
typedef float f32x4 __attribute__((ext_vector_type(4)));

// ---------------- fp32 -> bf16 cast, 4 elems/thread ----------------
__global__ __launch_bounds__(256) void cast_f32_bf16(const float* __restrict__ src,
                                                     __bf16* __restrict__ dst, int n4) {
  int i = blockIdx.x * blockDim.x + threadIdx.x;
  if (i >= n4) return;
  float4 v = ((const float4*)src)[i];
  bf16x4 o;
  o[0] = (__bf16)v.x; o[1] = (__bf16)v.y; o[2] = (__bf16)v.z; o[3] = (__bf16)v.w;
  ((bf16x4*)dst)[i] = o;
}

// ---------------- C = A * B^T ----------------
// A[M][K] bf16 row-major, B[N][K] bf16 row-major (i.e. output col n has
// contiguous K). C written fp32 (Cf) or bf16 (Cb), whichever is non-null.
// Block: 256 thr = 4 waves; block tile 128x128; wave tile 64x64; BK=32.
__global__ __launch_bounds__(256) void gemm_bt(const __bf16* __restrict__ A,
                                               const __bf16* __restrict__ Bm,
                                               __bf16* __restrict__ Cb,
                                               float* __restrict__ Cf,
                                               int M, int N, int K) {
  constexpr int LDP = 40;  // padded LDS row stride (32 data + 8 pad) -> 2-way bank alias = free
  __shared__ __attribute__((aligned(16))) __bf16 As[128 * LDP];
  __shared__ __attribute__((aligned(16))) __bf16 Bs[128 * LDP];
  const int m0 = blockIdx.x * 128;
  const int n0 = blockIdx.y * 128;
  const int tid = threadIdx.x;
  const int wave = tid >> 6;
  const int lane = tid & 63;
  const int lr = lane & 15;
  const int quad = lane >> 4;
  const int wm = (wave & 1) * 64;
  const int wn = (wave >> 1) * 64;
  f32x4 acc[4][4] = {};
  for (int k0 = 0; k0 < K; k0 += 32) {
    __syncthreads();
#pragma unroll
    for (int i = 0; i < 2; ++i) {
      int chunk = tid + i * 256;           // 0..511 : 128 rows x 4 chunks of 8 bf16
      int row = chunk >> 2;
      int cc = (chunk & 3) * 8;
      *(bf16x8*)&As[row * LDP + cc] = *(const bf16x8*)&A[(size_t)(m0 + row) * K + k0 + cc];
      *(bf16x8*)&Bs[row * LDP + cc] = *(const bf16x8*)&Bm[(size_t)(n0 + row) * K + k0 + cc];
    }
    __syncthreads();
    bf16x8 af[4], bf[4];
#pragma unroll
    for (int i = 0; i < 4; ++i)
      af[i] = *(bf16x8*)&As[(wm + i * 16 + lr) * LDP + quad * 8];
#pragma unroll
    for (int j = 0; j < 4; ++j)
      bf[j] = *(bf16x8*)&Bs[(wn + j * 16 + lr) * LDP + quad * 8];
#pragma unroll
    for (int i = 0; i < 4; ++i)
#pragma unroll
      for (int j = 0; j < 4; ++j)
        acc[i][j] = __builtin_amdgcn_mfma_f32_16x16x32_bf16(af[i], bf[j], acc[i][j], 0, 0, 0);
  }
  // D layout: col = lane&15, row = quad*4 + r  (m89-verified)
#pragma unroll
  for (int i = 0; i < 4; ++i) {
#pragma unroll
    for (int j = 0; j < 4; ++j) {
      int gm = m0 + wm + i * 16 + quad * 4;
      int gn = n0 + wn + j * 16 + lr;
      if (Cf) {
#pragma unroll
        for (int r = 0; r < 4; ++r) Cf[(size_t)(gm + r) * N + gn] = acc[i][j][r];
      } else {
#pragma unroll
        for (int r = 0; r < 4; ++r) Cb[(size_t)(gm + r) * N + gn] = (__bf16)acc[i][j][r];
      }
    }
  }
}

// ---------------- in-place RoPE on q & k sections of qkv ----------------
// one thread per (row, h, which, i) handles the (i, i+8) pair of the first 16 dims
__global__ __launch_bounds__(256) void rope_kernel(__bf16* __restrict__ qkv,
                                                   const float* __restrict__ cosp,
                                                   const float* __restrict__ sinp,
                                                   int total) {
  int idx = blockIdx.x * blockDim.x + threadIdx.x;
  if (idx >= total) return;
  int i = idx & 7;
  int which = (idx >> 3) & 1;          // 0 = q, 1 = k
  int rem = idx >> 4;                  // row*NH + h
  int h = rem % NH_DIM;
  int row = rem / NH_DIM;              // b*T + t
  int t = row & (T_DIM - 1);
  float c = cosp[t * 8 + i];
  float s = sinp[t * 8 + i];
  size_t base = (size_t)row * QKV_LD + which * C_DIM + h * HD_DIM;
  float r1 = (float)qkv[base + i];
  float r2 = (float)qkv[base + 8 + i];
  qkv[base + i]     = (__bf16)(r1 * c - r2 * s);
  qkv[base + 8 + i] = (__bf16)(r2 * c + r1 * s);
}

// ---------------- causal flash attention ----------------
// grid (8 qtiles, NH, B), 256 thr = 4 waves; wave handles 16 q-rows.
__global__ __launch_bounds__(256) void attn_kernel(const __bf16* __restrict__ qkv,
                                                   __bf16* __restrict__ o) {
  __shared__ __attribute__((aligned(16))) __bf16 Pl[4][16][72];  // per-wave P strip
  const int qt = blockIdx.x;
  const int h = blockIdx.y;
  const int b = blockIdx.z;
  const int wave = threadIdx.x >> 6;
  const int lane = threadIdx.x & 63;
  const int lr = lane & 15;
  const int quad = lane >> 4;
  const __bf16* qbase = qkv + (size_t)b * T_DIM * QKV_LD + h * HD_DIM;
  const __bf16* kbase = qbase + C_DIM;
  const __bf16* vbase = qbase + 2 * C_DIM;
  const int qrow0 = qt * 64 + wave * 16;  // first q row of this wave within batch b
  // Q A-fragments: A[m=lane&15][k=quad*8+j], 2 k-steps of 32 over HD=64 (m120-verified A layout)
  bf16x8 qf[2];
#pragma unroll
  for (int ks = 0; ks < 2; ++ks)
    qf[ks] = *(const bf16x8*)&qbase[(size_t)(qrow0 + lr) * QKV_LD + ks * 32 + quad * 8];
  f32x4 oacc[4] = {};
  float m_i[4], l_i[4];
#pragma unroll
  for (int r = 0; r < 4; ++r) { m_i[r] = -3.0e38f; l_i[r] = 0.f; }
  const float kScale = 0.18033688011112042f;  // (1/sqrt(64)) * log2(e)
  for (int kt = 0; kt <= qt; ++kt) {
    // S strip [16 q rows][64 keys], D layout: row = quad*4+r, col(key) = j*16 + lr
    f32x4 sj[4];
#pragma unroll
    for (int j = 0; j < 4; ++j) {
      f32x4 z = {};
#pragma unroll
      for (int ks = 0; ks < 2; ++ks) {
        bf16x8 kf = *(const bf16x8*)&kbase[(size_t)(kt * 64 + j * 16 + lr) * QKV_LD + ks * 32 + quad * 8];
        z = __builtin_amdgcn_mfma_f32_16x16x32_bf16(qf[ks], kf, z, 0, 0, 0);
      }
      sj[j] = z;
    }
    float mloc[4] = {-3.0e38f, -3.0e38f, -3.0e38f, -3.0e38f};
#pragma unroll
    for (int j = 0; j < 4; ++j)
#pragma unroll
      for (int r = 0; r < 4; ++r) {
        float v = sj[j][r] * kScale;
        if (kt == qt) {
          int col = kt * 64 + j * 16 + lr;
          int rowq = qrow0 + quad * 4 + r;
          if (col > rowq) v = -3.0e38f;
        }
        sj[j][r] = v;
        mloc[r] = fmaxf(mloc[r], v);
      }
    // row reductions across the 16 lanes (lr) sharing each row
#pragma unroll
    for (int off = 1; off < 16; off <<= 1)
#pragma unroll
      for (int r = 0; r < 4; ++r)
        mloc[r] = fmaxf(mloc[r], __shfl_xor(mloc[r], off, 64));
    float alpha[4];
#pragma unroll
    for (int r = 0; r < 4; ++r) {
      float mn = fmaxf(m_i[r], mloc[r]);
      alpha[r] = exp2f(m_i[r] - mn);
      m_i[r] = mn;
    }
    float rs[4] = {0.f, 0.f, 0.f, 0.f};
#pragma unroll
    for (int j = 0; j < 4; ++j)
#pragma unroll
      for (int r = 0; r < 4; ++r) {
        float p = exp2f(sj[j][r] - m_i[r]);
        rs[r] += p;
        Pl[wave][quad * 4 + r][j * 16 + lr] = (__bf16)p;  // C-layout -> LDS
      }
#pragma unroll
    for (int off = 1; off < 16; off <<= 1)
#pragma unroll
      for (int r = 0; r < 4; ++r)
        rs[r] += __shfl_xor(rs[r], off, 64);
#pragma unroll
    for (int r = 0; r < 4; ++r) l_i[r] = l_i[r] * alpha[r] + rs[r];
#pragma unroll
    for (int dt = 0; dt < 4; ++dt)
#pragma unroll
      for (int r = 0; r < 4; ++r) oacc[dt][r] *= alpha[r];
    __syncthreads();
    // P back out of LDS in A-operand layout
    bf16x8 pf[2];
#pragma unroll
    for (int ks = 0; ks < 2; ++ks)
      pf[ks] = *(const bf16x8*)&Pl[wave][lr][ks * 32 + quad * 8];
    // V B-fragments: B[k=key][n=d]; scalar gather (keys strided by QKV_LD)
#pragma unroll
    for (int dt = 0; dt < 4; ++dt) {
#pragma unroll
      for (int ks = 0; ks < 2; ++ks) {
        bf16x8 vf;
#pragma unroll
        for (int jj = 0; jj < 8; ++jj)
          vf[jj] = vbase[(size_t)(kt * 64 + ks * 32 + quad * 8 + jj) * QKV_LD + dt * 16 + lr];
        oacc[dt] = __builtin_amdgcn_mfma_f32_16x16x32_bf16(pf[ks], vf, oacc[dt], 0, 0, 0);
      }
    }
    __syncthreads();
  }
#pragma unroll
  for (int r = 0; r < 4; ++r) l_i[r] = 1.f / l_i[r];
#pragma unroll
  for (int dt = 0; dt < 4; ++dt)
#pragma unroll
    for (int r = 0; r < 4; ++r) {
      size_t row = (size_t)b * T_DIM + qrow0 + quad * 4 + r;
      o[row * C_DIM + h * HD_DIM + dt * 16 + lr] = (__bf16)(oacc[dt][r] * l_i[r]);
    }
}

extern "C" void kernel_launch(void* const* d_in, const int* in_sizes, int n_in,
                              void* d_out, int out_size, void* d_ws, size_t ws_size,
                              hipStream_t stream) {
  const float* x    = (const float*)d_in[0];  // [B,T,C]
  const float* wqkv = (const float*)d_in[1];  // [3C,C]
  const float* wout = (const float*)d_in[2];  // [C,C]
  const float* cosp = (const float*)d_in[3];  // [1,1,512,8]
  const float* sinp = (const float*)d_in[4];  // [1,1,512,8]
  float* out = (float*)d_out;

  char* ws = (char*)d_ws;
  __bf16* xb    = (__bf16*)(ws);                    // 25165824 elems
  __bf16* wqkvb = (__bf16*)(ws + 50331648);         // 442368
  __bf16* woutb = (__bf16*)(ws + 51216384);         // 147456
  __bf16* qkvb  = (__bf16*)(ws + 51511296);         // 75497472
  __bf16* ob    = (__bf16*)(ws + 202506240);        // 25165824
  // total ws use: 252837888 bytes

  const int M = B_DIM * T_DIM;  // 65536

  cast_f32_bf16<<<24576, 256, 0, stream>>>(x, xb, 6291456);
  cast_f32_bf16<<<432, 256, 0, stream>>>(wqkv, wqkvb, 110592);
  cast_f32_bf16<<<144, 256, 0, stream>>>(wout, woutb, 36864);

  // qkv = x @ Wqkv^T : [65536][1152] bf16
  gemm_bt<<<dim3(M / 128, QKV_LD / 128), 256, 0, stream>>>(
      xb, wqkvb, qkvb, (float*)nullptr, M, QKV_LD, C_DIM);

  // RoPE in-place on q,k
  {
    int total = M * NH_DIM * 2 * 8;  // 6291456
    rope_kernel<<<(total + 255) / 256, 256, 0, stream>>>(qkvb, cosp, sinp, total);
  }

  // causal flash attention -> o [65536][384] bf16
  attn_kernel<<<dim3(T_DIM / 64, NH_DIM, B_DIM), 256, 0, stream>>>(qkvb, ob);

  // out = o @ Wout^T : fp32
  gemm_bt<<<dim3(M / 128, C_DIM / 128), 256, 0, stream>>>(
      ob, woutb, (__bf16*)nullptr, out, M, C_DIM, C_DIM);
}

// Round 4
// 534.874 us; speedup vs baseline: 1.2361x; 1.2361x over previous
//
#include <hip/hip_runtime.h>

#define B_DIM 128
#define T_DIM 512
#define C_DIM 384
#define NH_DIM 6
#define HD_DIM 64
#define QKV_LD 1152  // 3*C

typedef __bf16 bf16x8 __attribute__((ext_vector_type(8)));
typedef __bf16 bf16x4 __attribute__((ext_vector_type(4)));
typedef float f32x4 __attribute__((ext_vector_type(4)));

// ---------------- fp32 -> bf16 cast, 4 elems/thread ----------------
__global__ __launch_bounds__(256) void cast_f32_bf16(const float* __restrict__ src,
                                                     __bf16* __restrict__ dst, int n4) {
  int i = blockIdx.x * blockDim.x + threadIdx.x;
  if (i >= n4) return;
  float4 v = ((const float4*)src)[i];
  bf16x4 o;
  o[0] = (__bf16)v.x; o[1] = (__bf16)v.y; o[2] = (__bf16)v.z; o[3] = (__bf16)v.w;
  ((bf16x4*)dst)[i] = o;
}

// ---------------- C = A * B^T ----------------
// A[M][K] bf16 row-major, B[N][K] bf16 row-major. C written fp32 (Cf) or bf16
// (Cb), whichever is non-null.
// Block: 256 thr = 4 waves; block tile 128x128; wave tile 64x64; BK=32.
__global__ __launch_bounds__(256) void gemm_bt(const __bf16* __restrict__ A,
                                               const __bf16* __restrict__ Bm,
                                               __bf16* __restrict__ Cb,
                                               float* __restrict__ Cf,
                                               int M, int N, int K) {
  constexpr int LDP = 40;  // padded LDS row stride; 2-way bank alias = free (m136)
  __shared__ __attribute__((aligned(16))) __bf16 As[128 * LDP];
  __shared__ __attribute__((aligned(16))) __bf16 Bs[128 * LDP];
  const int m0 = blockIdx.x * 128;
  const int n0 = blockIdx.y * 128;
  const int tid = threadIdx.x;
  const int wave = tid >> 6;
  const int lane = tid & 63;
  const int lr = lane & 15;
  const int quad = lane >> 4;
  const int wm = (wave & 1) * 64;
  const int wn = (wave >> 1) * 64;
  f32x4 acc[4][4] = {};
  for (int k0 = 0; k0 < K; k0 += 32) {
    __syncthreads();
#pragma unroll
    for (int i = 0; i < 2; ++i) {
      int chunk = tid + i * 256;           // 0..511 : 128 rows x 4 chunks of 8 bf16
      int row = chunk >> 2;
      int cc = (chunk & 3) * 8;
      *(bf16x8*)&As[row * LDP + cc] = *(const bf16x8*)&A[(size_t)(m0 + row) * K + k0 + cc];
      *(bf16x8*)&Bs[row * LDP + cc] = *(const bf16x8*)&Bm[(size_t)(n0 + row) * K + k0 + cc];
    }
    __syncthreads();
    bf16x8 af[4], bf[4];
#pragma unroll
    for (int i = 0; i < 4; ++i)
      af[i] = *(bf16x8*)&As[(wm + i * 16 + lr) * LDP + quad * 8];
#pragma unroll
    for (int j = 0; j < 4; ++j)
      bf[j] = *(bf16x8*)&Bs[(wn + j * 16 + lr) * LDP + quad * 8];
#pragma unroll
    for (int i = 0; i < 4; ++i)
#pragma unroll
      for (int j = 0; j < 4; ++j)
        acc[i][j] = __builtin_amdgcn_mfma_f32_16x16x32_bf16(af[i], bf[j], acc[i][j], 0, 0, 0);
  }
  // D layout: col = lane&15, row = quad*4 + r  (m89-verified)
#pragma unroll
  for (int i = 0; i < 4; ++i) {
#pragma unroll
    for (int j = 0; j < 4; ++j) {
      int gm = m0 + wm + i * 16 + quad * 4;
      int gn = n0 + wn + j * 16 + lr;
      if (Cf) {
#pragma unroll
        for (int r = 0; r < 4; ++r) Cf[(size_t)(gm + r) * N + gn] = acc[i][j][r];
      } else {
#pragma unroll
        for (int r = 0; r < 4; ++r) Cb[(size_t)(gm + r) * N + gn] = (__bf16)acc[i][j][r];
      }
    }
  }
}

// ---------------- in-place RoPE on q & k sections of qkv ----------------
__global__ __launch_bounds__(256) void rope_kernel(__bf16* __restrict__ qkv,
                                                   const float* __restrict__ cosp,
                                                   const float* __restrict__ sinp,
                                                   int total) {
  int idx = blockIdx.x * blockDim.x + threadIdx.x;
  if (idx >= total) return;
  int i = idx & 7;
  int which = (idx >> 3) & 1;          // 0 = q, 1 = k
  int rem = idx >> 4;                  // row*NH + h
  int h = rem % NH_DIM;
  int row = rem / NH_DIM;              // b*T + t
  int t = row & (T_DIM - 1);
  float c = cosp[t * 8 + i];
  float s = sinp[t * 8 + i];
  size_t base = (size_t)row * QKV_LD + which * C_DIM + h * HD_DIM;
  float r1 = (float)qkv[base + i];
  float r2 = (float)qkv[base + 8 + i];
  qkv[base + i]     = (__bf16)(r1 * c - r2 * s);
  qkv[base + 8 + i] = (__bf16)(r2 * c + r1 * s);
}

// ---------------- V transpose: vt[b][h][d][t] <- qkv[b*T+t][768 + h*64 + d] ----------------
// 64x64 tile via LDS; both global sides are bf16x8 vectorized. The scalar LDS
// reads in phase 2 are 16-way bank-conflicted but total ~2us across the grid.
__global__ __launch_bounds__(256) void transpose_v(const __bf16* __restrict__ qkv,
                                                   __bf16* __restrict__ vt) {
  __shared__ __attribute__((aligned(16))) __bf16 Tl[64][72];
  const int tt = blockIdx.x;   // t-tile (0..7)
  const int h = blockIdx.y;
  const int b = blockIdx.z;
  const int tid = threadIdx.x;
  const __bf16* src = qkv + (size_t)b * T_DIM * QKV_LD + 2 * C_DIM + h * HD_DIM;
#pragma unroll
  for (int i = 0; i < 2; ++i) {
    int c = tid + i * 256;     // 512 chunks: row=t-in-tile, cc=d base
    int row = c >> 3, cc = (c & 7) * 8;
    *(bf16x8*)&Tl[row][cc] = *(const bf16x8*)&src[(size_t)(tt * 64 + row) * QKV_LD + cc];
  }
  __syncthreads();
  __bf16* dst = vt + (size_t)(b * NH_DIM + h) * HD_DIM * T_DIM + tt * 64;
#pragma unroll
  for (int i = 0; i < 2; ++i) {
    int c = tid + i * 256;     // drow=d, tc=t base
    int drow = c >> 3, tc = (c & 7) * 8;
    bf16x8 v;
#pragma unroll
    for (int j = 0; j < 8; ++j) v[j] = Tl[tc + j][drow];
    *(bf16x8*)&dst[(size_t)drow * T_DIM + tc] = v;
  }
}

// ---------------- causal flash attention ----------------
// grid (8 qtiles, NH, B), 256 thr = 4 waves; wave handles 16 q-rows.
// K/V tiles staged in LDS once per block (coalesced), shared by all 4 waves.
// V comes pre-transposed as vt[b][h][d][t].
__global__ __launch_bounds__(256) void attn_kernel(const __bf16* __restrict__ qkv,
                                                   const __bf16* __restrict__ vt,
                                                   __bf16* __restrict__ o) {
  constexpr int LDK = 72;  // row stride: 144B, 16B-aligned vector accesses
  __shared__ __attribute__((aligned(16))) __bf16 Ks[64 * LDK];   // [key][d]
  __shared__ __attribute__((aligned(16))) __bf16 Vs[64 * LDK];   // [d][key]
  __shared__ __attribute__((aligned(16))) __bf16 Pl[4][16][72];  // per-wave P strip
  const int qt = blockIdx.x;
  const int h = blockIdx.y;
  const int b = blockIdx.z;
  const int tid = threadIdx.x;
  const int wave = tid >> 6;
  const int lane = tid & 63;
  const int lr = lane & 15;
  const int quad = lane >> 4;
  const __bf16* qbase = qkv + (size_t)b * T_DIM * QKV_LD + h * HD_DIM;
  const __bf16* kbase = qbase + C_DIM;
  const __bf16* vtb = vt + (size_t)(b * NH_DIM + h) * HD_DIM * T_DIM;  // [d][t]
  const int qrow0 = qt * 64 + wave * 16;
  // Q A-fragments: A[m=lane&15][k=quad*8+j] (m120-verified A layout)
  bf16x8 qf[2];
#pragma unroll
  for (int ks = 0; ks < 2; ++ks)
    qf[ks] = *(const bf16x8*)&qbase[(size_t)(qrow0 + lr) * QKV_LD + ks * 32 + quad * 8];
  f32x4 oacc[4] = {};
  float m_i[4], l_i[4];
#pragma unroll
  for (int r = 0; r < 4; ++r) { m_i[r] = -3.0e38f; l_i[r] = 0.f; }
  const float kScale = 0.18033688011112042f;  // (1/sqrt(64)) * log2(e)
  for (int kt = 0; kt <= qt; ++kt) {
    __syncthreads();  // prev iteration's Ks/Vs reads done
#pragma unroll
    for (int i = 0; i < 2; ++i) {
      int c = tid + i * 256;   // 512 chunks: 64 rows x 8 chunks of 8 bf16
      int row = c >> 3;
      int cc = (c & 7) * 8;
      *(bf16x8*)&Ks[row * LDK + cc] =
          *(const bf16x8*)&kbase[(size_t)(kt * 64 + row) * QKV_LD + cc];
      *(bf16x8*)&Vs[row * LDK + cc] =
          *(const bf16x8*)&vtb[(size_t)row * T_DIM + kt * 64 + cc];
    }
    __syncthreads();
    // S strip [16 q rows][64 keys], D layout: row = quad*4+r, col(key) = j*16+lr
    f32x4 sj[4];
#pragma unroll
    for (int j = 0; j < 4; ++j) {
      f32x4 z = {};
#pragma unroll
      for (int ks = 0; ks < 2; ++ks) {
        bf16x8 kf = *(bf16x8*)&Ks[(j * 16 + lr) * LDK + ks * 32 + quad * 8];
        z = __builtin_amdgcn_mfma_f32_16x16x32_bf16(qf[ks], kf, z, 0, 0, 0);
      }
      sj[j] = z;
    }
    float mloc[4] = {-3.0e38f, -3.0e38f, -3.0e38f, -3.0e38f};
#pragma unroll
    for (int j = 0; j < 4; ++j)
#pragma unroll
      for (int r = 0; r < 4; ++r) {
        float v = sj[j][r] * kScale;
        if (kt == qt) {
          int col = kt * 64 + j * 16 + lr;
          int rowq = qrow0 + quad * 4 + r;
          if (col > rowq) v = -3.0e38f;
        }
        sj[j][r] = v;
        mloc[r] = fmaxf(mloc[r], v);
      }
#pragma unroll
    for (int off = 1; off < 16; off <<= 1)
#pragma unroll
      for (int r = 0; r < 4; ++r)
        mloc[r] = fmaxf(mloc[r], __shfl_xor(mloc[r], off, 64));
    float alpha[4];
#pragma unroll
    for (int r = 0; r < 4; ++r) {
      float mn = fmaxf(m_i[r], mloc[r]);
      alpha[r] = exp2f(m_i[r] - mn);
      m_i[r] = mn;
    }
    float rs[4] = {0.f, 0.f, 0.f, 0.f};
#pragma unroll
    for (int j = 0; j < 4; ++j)
#pragma unroll
      for (int r = 0; r < 4; ++r) {
        float p = exp2f(sj[j][r] - m_i[r]);
        rs[r] += p;
        Pl[wave][quad * 4 + r][j * 16 + lr] = (__bf16)p;  // C-layout -> per-wave LDS
      }
#pragma unroll
    for (int off = 1; off < 16; off <<= 1)
#pragma unroll
      for (int r = 0; r < 4; ++r)
        rs[r] += __shfl_xor(rs[r], off, 64);
#pragma unroll
    for (int r = 0; r < 4; ++r) l_i[r] = l_i[r] * alpha[r] + rs[r];
#pragma unroll
    for (int dt = 0; dt < 4; ++dt)
#pragma unroll
      for (int r = 0; r < 4; ++r) oacc[dt][r] *= alpha[r];
    // P out of LDS in A-operand layout (same-wave DS ordering: no barrier needed)
    bf16x8 pf[2];
#pragma unroll
    for (int ks = 0; ks < 2; ++ks)
      pf[ks] = *(bf16x8*)&Pl[wave][lr][ks * 32 + quad * 8];
    // V B-fragments from transposed LDS tile: B[n=d][k=key], contiguous in key
#pragma unroll
    for (int dt = 0; dt < 4; ++dt) {
#pragma unroll
      for (int ks = 0; ks < 2; ++ks) {
        bf16x8 vf = *(bf16x8*)&Vs[(dt * 16 + lr) * LDK + ks * 32 + quad * 8];
        oacc[dt] = __builtin_amdgcn_mfma_f32_16x16x32_bf16(pf[ks], vf, oacc[dt], 0, 0, 0);
      }
    }
  }
#pragma unroll
  for (int r = 0; r < 4; ++r) l_i[r] = 1.f / l_i[r];
#pragma unroll
  for (int dt = 0; dt < 4; ++dt)
#pragma unroll
    for (int r = 0; r < 4; ++r) {
      size_t row = (size_t)b * T_DIM + qrow0 + quad * 4 + r;
      o[row * C_DIM + h * HD_DIM + dt * 16 + lr] = (__bf16)(oacc[dt][r] * l_i[r]);
    }
}

extern "C" void kernel_launch(void* const* d_in, const int* in_sizes, int n_in,
                              void* d_out, int out_size, void* d_ws, size_t ws_size,
                              hipStream_t stream) {
  const float* x    = (const float*)d_in[0];  // [B,T,C]
  const float* wqkv = (const float*)d_in[1];  // [3C,C]
  const float* wout = (const float*)d_in[2];  // [C,C]
  const float* cosp = (const float*)d_in[3];  // [1,1,512,8]
  const float* sinp = (const float*)d_in[4];  // [1,1,512,8]
  float* out = (float*)d_out;

  char* ws = (char*)d_ws;
  __bf16* xb    = (__bf16*)(ws);                    // 25165824 elems (50331648 B)
  __bf16* wqkvb = (__bf16*)(ws + 50331648);         // 442368
  __bf16* woutb = (__bf16*)(ws + 51216384);         // 147456
  __bf16* qkvb  = (__bf16*)(ws + 51511296);         // 75497472
  __bf16* ob    = (__bf16*)(ws + 202506240);        // 25165824
  // vt reuses xb's region: xb is dead once the QKV GEMM has completed, and
  // transpose_v runs strictly after it on the same stream. Exact fit: 50331648 B.
  __bf16* vtb   = xb;
  // total ws use: 252837888 bytes (same as the R1 kernel that ran clean)

  const int M = B_DIM * T_DIM;  // 65536

  cast_f32_bf16<<<24576, 256, 0, stream>>>(x, xb, 6291456);
  cast_f32_bf16<<<432, 256, 0, stream>>>(wqkv, wqkvb, 110592);
  cast_f32_bf16<<<144, 256, 0, stream>>>(wout, woutb, 36864);

  // qkv = x @ Wqkv^T : [65536][1152] bf16
  gemm_bt<<<dim3(M / 128, QKV_LD / 128), 256, 0, stream>>>(
      xb, wqkvb, qkvb, (float*)nullptr, M, QKV_LD, C_DIM);

  // RoPE in-place on q,k
  {
    int total = M * NH_DIM * 2 * 8;  // 6291456
    rope_kernel<<<(total + 255) / 256, 256, 0, stream>>>(qkvb, cosp, sinp, total);
  }

  // V -> vt[b][h][d][t] (xb region; xb dead after the QKV GEMM)
  transpose_v<<<dim3(T_DIM / 64, NH_DIM, B_DIM), 256, 0, stream>>>(qkvb, vtb);

  // causal flash attention -> o [65536][384] bf16
  attn_kernel<<<dim3(T_DIM / 64, NH_DIM, B_DIM), 256, 0, stream>>>(qkvb, vtb, ob);

  // out = o @ Wout^T : fp32
  gemm_bt<<<dim3(M / 128, C_DIM / 128), 256, 0, stream>>>(
      ob, woutb, (__bf16*)nullptr, out, M, C_DIM, C_DIM);
}